// Round 2
// baseline (3697.783 us; speedup 1.0000x reference)
//
#include <hip/hip_runtime.h>

// ---------------------------------------------------------------------------
// UnetrUpBlockSLA — fp32 correctness-first baseline (r1: ws aliasing, 222 MB).
// Pipeline (all fused where cheap):
//   k_up       : ConvTranspose2d(k=2,s=2)  inp[16,256,48,48] -> UP[16,128,96,96]
//   (concat is virtual: x = [UP ; skip], channel select in consumers)
//   k_colmean  : per-(b,c) spatial mean of x -> XMEAN[16,256]
//   k_gate     : z = xmean @ Wg^T + bg ; sparsemax -> g[16,4]   (g1, g3)
//   k_mixw13   : WMIX1[b]=sum_k g1 A1 ; WRES[b]=conv3_w + sum_k g3 A3
//   k_conv<256,true>  : BUF1 = conv3x3(x,conv1_w) + WMIX1[b]@x  (+IN stats)
//   k_conv<256,false> : BUF3 = WRES[b] @ x                      (+IN stats)
//   k_norm1    : BUF1 = lrelu(instnorm(BUF1)) in-place, o1mean for gate2
//   k_gate / k_mixw2 -> WMIX2
//   k_conv<128,true>  : BUF2 = conv3x3(BUF1,conv2_w)+WMIX2[b]@BUF1 (+stats)
//                       (BUF2 aliases UP — UP is dead by then)
//   k_final    : d_out = lrelu( IN(BUF2) + IN(BUF3) )
// ---------------------------------------------------------------------------

#define NB   16
#define C2   256       // 2*Cout (concat channels)
#define C1   128       // Cout
#define HO   96
#define WO   96
#define NPIX 9216
#define HI   48
#define WI   48

// workspace offsets (floats). BUF2 aliases UP (dead after the two 256-ch convs).
#define OFF_UP    0ull
#define OFF_BUF2  0ull
#define OFF_BUF1  18874368ull
#define OFF_BUF3  37748736ull
#define OFF_WMIX1 56623104ull   // [16][128][256]
#define OFF_WRES  57147392ull   // [16][128][256]
#define OFF_WMIX2 57671680ull   // [16][128][128]
#define OFF_XMEAN 57933824ull   // [16][256]
#define OFF_O1M   57937920ull   // [16][128]
#define OFF_G1    57939968ull
#define OFF_G2    57940032ull
#define OFF_G3    57940096ull
#define OFF_STATS 57940160ull   // 6 * 2048 floats (zeroed each call)

// ---------------------------------------------------------------------------
// Transposed conv 2x2 stride2: up[b,o,2i+di,2j+dj] = sum_c inp[b,c,i,j]*wt[c,o,di,dj]
// GEMM-style: block = 16 o x (16i x 16j) px tile; thread = 4o x 4j x 4taps.
__global__ __launch_bounds__(256) void k_up(const float* __restrict__ inp,
                                            const float* __restrict__ wt,
                                            float* __restrict__ up) {
  int b = blockIdx.y;
  int oc = blockIdx.x & 7;       // 8 o-chunks of 16
  int tile = blockIdx.x >> 3;    // 0..8  (3x3 tiles of 16x16 over 48x48)
  int i0 = (tile / 3) * 16, j0 = (tile % 3) * 16;
  int t = threadIdx.x;
  int og = t >> 6, pg = t & 63, pi = pg >> 2, pj4 = pg & 3;

  __shared__ float  s_in[16 * 272];   // [ci][i][17]
  __shared__ float4 s_w4[256];        // [ci][o] (4 taps per float4)

  float4 acc[4][4];
#pragma unroll
  for (int j = 0; j < 4; j++)
#pragma unroll
    for (int oo = 0; oo < 4; oo++) acc[j][oo] = make_float4(0.f, 0.f, 0.f, 0.f);

  for (int cc = 0; cc < 16; ++cc) {
#pragma unroll
    for (int it = 0; it < 16; ++it) {
      int flat = it * 256 + t;
      int ci = flat >> 8, i = (flat >> 4) & 15, j = flat & 15;
      s_in[ci * 272 + i * 17 + j] =
          inp[((size_t)(b * C2 + cc * 16 + ci) * HI + (i0 + i)) * WI + (j0 + j)];
    }
    {
      int ci = t >> 4, o = t & 15;
      s_w4[ci * 16 + o] = ((const float4*)wt)[(size_t)(cc * 16 + ci) * C1 + oc * 16 + o];
    }
    __syncthreads();
#pragma unroll
    for (int ci = 0; ci < 16; ++ci) {
      float iv[4];
#pragma unroll
      for (int q = 0; q < 4; q++) iv[q] = s_in[ci * 272 + pi * 17 + pj4 * 4 + q];
#pragma unroll
      for (int oo = 0; oo < 4; oo++) {
        float4 w = s_w4[ci * 16 + og * 4 + oo];
#pragma unroll
        for (int j = 0; j < 4; j++) {
          acc[j][oo].x += iv[j] * w.x; acc[j][oo].y += iv[j] * w.y;
          acc[j][oo].z += iv[j] * w.z; acc[j][oo].w += iv[j] * w.w;
        }
      }
    }
    __syncthreads();
  }
  int orow = 2 * (i0 + pi);
#pragma unroll
  for (int oo = 0; oo < 4; oo++) {
    int o = oc * 16 + og * 4 + oo;
    float* base = up + (size_t)(b * C1 + o) * HO * WO;
#pragma unroll
    for (int j = 0; j < 4; j++) {
      int jj = j0 + pj4 * 4 + j;
      *(float2*)(base + (size_t)orow * WO + 2 * jj)       = make_float2(acc[j][oo].x, acc[j][oo].y);
      *(float2*)(base + (size_t)(orow + 1) * WO + 2 * jj) = make_float2(acc[j][oo].z, acc[j][oo].w);
    }
  }
}

// ---------------------------------------------------------------------------
__global__ __launch_bounds__(256) void k_colmean(const float* __restrict__ up,
                                                 const float* __restrict__ skip,
                                                 float* __restrict__ xmean) {
  int bc = blockIdx.x;  // b*256 + c
  int b = bc >> 8, c = bc & 255;
  const float* src = (c < C1) ? up + (size_t)(b * C1 + c) * NPIX
                              : skip + (size_t)(b * C1 + (c - C1)) * NPIX;
  const float4* s4 = (const float4*)src;
  float sum = 0.f;
#pragma unroll
  for (int it = 0; it < 9; ++it) {
    float4 v = s4[it * 256 + threadIdx.x];
    sum += v.x + v.y + v.z + v.w;
  }
  for (int off = 32; off; off >>= 1) sum += __shfl_xor(sum, off);
  __shared__ float sl[4];
  if ((threadIdx.x & 63) == 0) sl[threadIdx.x >> 6] = sum;
  __syncthreads();
  if (threadIdx.x == 0) xmean[bc] = (sl[0] + sl[1] + sl[2] + sl[3]) * (1.0f / NPIX);
}

// ---------------------------------------------------------------------------
// z[k] = xm[b]·Wg[k] + bg[k]; sparsemax over K=4; one block per b.
__global__ __launch_bounds__(256) void k_gate(const float* __restrict__ xm, int CI,
                                              const float* __restrict__ Wg,
                                              const float* __restrict__ bg,
                                              float* __restrict__ g) {
  int b = blockIdx.x;
  int w = threadIdx.x >> 6, lane = threadIdx.x & 63;
  float sum = 0.f;
  for (int i = lane; i < CI; i += 64) sum += xm[b * CI + i] * Wg[w * CI + i];
  for (int off = 32; off; off >>= 1) sum += __shfl_xor(sum, off);
  __shared__ float z[4];
  if (lane == 0) z[w] = sum + bg[w];
  __syncthreads();
  if (threadIdx.x == 0) {
    float zz[4] = {z[0], z[1], z[2], z[3]};
    float a0 = zz[0], a1 = zz[1], a2 = zz[2], a3 = zz[3], tmp;
    if (a0 < a1) { tmp = a0; a0 = a1; a1 = tmp; }
    if (a2 < a3) { tmp = a2; a2 = a3; a3 = tmp; }
    if (a0 < a2) { tmp = a0; a0 = a2; a2 = tmp; }
    if (a1 < a3) { tmp = a1; a1 = a3; a3 = tmp; }
    if (a1 < a2) { tmp = a1; a1 = a2; a2 = tmp; }
    float cs0 = a0, cs1 = cs0 + a1, cs2 = cs1 + a2, cs3 = cs2 + a3;
    int km = (1.f + 1.f * a0 > cs0) + (1.f + 2.f * a1 > cs1) +
             (1.f + 3.f * a2 > cs2) + (1.f + 4.f * a3 > cs3);
    float csk = (km == 1) ? cs0 : (km == 2) ? cs1 : (km == 3) ? cs2 : cs3;
    float tau = (csk - 1.f) / (float)km;
#pragma unroll
    for (int k = 0; k < 4; k++) g[b * 4 + k] = fmaxf(zz[k] - tau, 0.f);
  }
}

// ---------------------------------------------------------------------------
__global__ __launch_bounds__(256) void k_mixw13(const float* __restrict__ A1,
                                                const float* __restrict__ A3,
                                                const float* __restrict__ c3w,
                                                const float* __restrict__ g1,
                                                const float* __restrict__ g3,
                                                float* __restrict__ wmix1,
                                                float* __restrict__ wres) {
  int idx = blockIdx.x * 256 + threadIdx.x;  // [b][o][i], i fastest
  int i = idx & 255, o = (idx >> 8) & 127, b = idx >> 15;
  size_t oi = (size_t)o * C2 + i;
  float m1 = 0.f, m3 = 0.f;
#pragma unroll
  for (int k = 0; k < 4; k++) {
    m1 += g1[b * 4 + k] * A1[(size_t)k * C1 * C2 + oi];
    m3 += g3[b * 4 + k] * A3[(size_t)k * C1 * C2 + oi];
  }
  wmix1[idx] = m1;
  wres[idx] = c3w[oi] + m3;
}

__global__ __launch_bounds__(256) void k_mixw2(const float* __restrict__ A2,
                                               const float* __restrict__ g2,
                                               float* __restrict__ wmix2) {
  int idx = blockIdx.x * 256 + threadIdx.x;  // [b][o][i<128]
  int i = idx & 127, o = (idx >> 7) & 127, b = idx >> 14;
  float m = 0.f;
#pragma unroll
  for (int k = 0; k < 4; k++) m += g2[b * 4 + k] * A2[((size_t)k * C1 + o) * C1 + i];
  wmix2[idx] = m;
}

// ---------------------------------------------------------------------------
// Fused conv3x3 (+ per-sample 1x1 "center tap") with instnorm stat atomics.
// Block: 32 o x (16 rows x 32 cols); thread: 8 o x 8 px (outer product).
template <int CI, bool DO3X3>
__global__ __launch_bounds__(256, 2) void k_conv(const float* __restrict__ src0,
                                                 const float* __restrict__ src1,
                                                 const float* __restrict__ convw,
                                                 const float* __restrict__ wmix,
                                                 float* __restrict__ dst,
                                                 float* __restrict__ ssum,
                                                 float* __restrict__ ssq) {
  int b = blockIdx.z;
  int o0 = blockIdx.y * 32;
  int rt = blockIdx.x / 3, ct = blockIdx.x % 3;
  int r0 = rt * 16, c0 = ct * 32;
  int t = threadIdx.x;
  int og = t >> 6, rr = (t >> 2) & 15, cg = t & 3;

  __shared__ float s_in[8 * 666];                // [ci][18][37]
  __shared__ __align__(16) float s_w[8 * 320];   // [ci][tap0..8,9=mix][32 o]

  float acc[8][8];
#pragma unroll
  for (int p = 0; p < 8; p++)
#pragma unroll
    for (int oo = 0; oo < 8; oo++) acc[p][oo] = 0.f;

  for (int cc = 0; cc < CI / 8; ++cc) {
    for (int flat = t; flat < 4896; flat += 256) {
      int ci = flat / 612;
      int rem = flat - ci * 612;
      int lr = rem / 34;
      int lc = rem - lr * 34;
      int gr = r0 - 1 + lr, gc = c0 - 1 + lc;
      int cful = cc * 8 + ci;
      float v = 0.f;
      if (gr >= 0 && gr < HO && gc >= 0 && gc < WO) {
        if constexpr (CI == 256) {
          v = (cful < C1) ? src0[((size_t)(b * C1 + cful) * HO + gr) * WO + gc]
                          : src1[((size_t)(b * C1 + cful - C1) * HO + gr) * WO + gc];
        } else {
          v = src0[((size_t)(b * CI + cful) * HO + gr) * WO + gc];
        }
      }
      s_in[ci * 666 + lr * 37 + lc] = v;
    }
    if constexpr (DO3X3) {
      for (int flat = t; flat < 2304; flat += 256) {
        int ci = flat / 288;
        int rem = flat - ci * 288;
        int tap = rem >> 5, o = rem & 31;
        s_w[ci * 320 + tap * 32 + o] = convw[((size_t)(o0 + o) * CI + cc * 8 + ci) * 9 + tap];
      }
    }
    {
      int ci = t >> 5, o = t & 31;
      s_w[ci * 320 + 288 + o] = wmix[((size_t)b * C1 + o0 + o) * CI + cc * 8 + ci];
    }
    __syncthreads();
#pragma unroll
    for (int ci = 0; ci < 8; ++ci) {
      const float* ibase = s_in + ci * 666 + rr * 37 + cg * 8;
      if constexpr (DO3X3) {
        float iv[3][10];
#pragma unroll
        for (int dr = 0; dr < 3; ++dr)
#pragma unroll
          for (int q = 0; q < 10; ++q) iv[dr][q] = ibase[dr * 37 + q];
#pragma unroll
        for (int tap = 0; tap < 9; ++tap) {
          int dr = tap / 3, dc = tap % 3;
          const float4* w4 = (const float4*)(s_w + ci * 320 + tap * 32 + og * 8);
          float4 wa = w4[0], wb = w4[1];
#pragma unroll
          for (int p = 0; p < 8; ++p) {
            float x = iv[dr][p + dc];
            acc[p][0] += x * wa.x; acc[p][1] += x * wa.y;
            acc[p][2] += x * wa.z; acc[p][3] += x * wa.w;
            acc[p][4] += x * wb.x; acc[p][5] += x * wb.y;
            acc[p][6] += x * wb.z; acc[p][7] += x * wb.w;
          }
        }
        {
          const float4* w4 = (const float4*)(s_w + ci * 320 + 288 + og * 8);
          float4 wa = w4[0], wb = w4[1];
#pragma unroll
          for (int p = 0; p < 8; ++p) {
            float x = iv[1][p + 1];
            acc[p][0] += x * wa.x; acc[p][1] += x * wa.y;
            acc[p][2] += x * wa.z; acc[p][3] += x * wa.w;
            acc[p][4] += x * wb.x; acc[p][5] += x * wb.y;
            acc[p][6] += x * wb.z; acc[p][7] += x * wb.w;
          }
        }
      } else {
        float ivc[8];
#pragma unroll
        for (int p = 0; p < 8; ++p) ivc[p] = ibase[37 + p + 1];
        const float4* w4 = (const float4*)(s_w + ci * 320 + 288 + og * 8);
        float4 wa = w4[0], wb = w4[1];
#pragma unroll
        for (int p = 0; p < 8; ++p) {
          float x = ivc[p];
          acc[p][0] += x * wa.x; acc[p][1] += x * wa.y;
          acc[p][2] += x * wa.z; acc[p][3] += x * wa.w;
          acc[p][4] += x * wb.x; acc[p][5] += x * wb.y;
          acc[p][6] += x * wb.z; acc[p][7] += x * wb.w;
        }
      }
    }
    __syncthreads();
  }

  int row = r0 + rr, col = c0 + cg * 8;
#pragma unroll
  for (int oo = 0; oo < 8; ++oo) {
    int o = o0 + og * 8 + oo;
    float* dp = dst + ((size_t)(b * C1 + o) * HO + row) * WO + col;
    ((float4*)dp)[0] = make_float4(acc[0][oo], acc[1][oo], acc[2][oo], acc[3][oo]);
    ((float4*)dp)[1] = make_float4(acc[4][oo], acc[5][oo], acc[6][oo], acc[7][oo]);
    float s = 0.f, q = 0.f;
#pragma unroll
    for (int p = 0; p < 8; ++p) { s += acc[p][oo]; q += acc[p][oo] * acc[p][oo]; }
    for (int off = 32; off; off >>= 1) { s += __shfl_xor(s, off); q += __shfl_xor(q, off); }
    if ((t & 63) == 0) {
      atomicAdd(&ssum[b * C1 + o], s);
      atomicAdd(&ssq[b * C1 + o], q);
    }
  }
}

// ---------------------------------------------------------------------------
__global__ __launch_bounds__(256) void k_norm1(float* __restrict__ buf,
                                               const float* __restrict__ ssum,
                                               const float* __restrict__ ssq,
                                               float* __restrict__ omean) {
  int bc = blockIdx.x;
  float mean = ssum[bc] * (1.0f / NPIX);
  float var = ssq[bc] * (1.0f / NPIX) - mean * mean;
  float rinv = rsqrtf(var + 1e-5f);
  float4* p4 = (float4*)(buf + (size_t)bc * NPIX);
  float lsum = 0.f;
#pragma unroll
  for (int it = 0; it < 9; ++it) {
    float4 v = p4[it * 256 + threadIdx.x];
    float* vv = (float*)&v;
#pragma unroll
    for (int u = 0; u < 4; ++u) {
      float x = (vv[u] - mean) * rinv;
      x = (x >= 0.f) ? x : 0.01f * x;
      vv[u] = x;
      lsum += x;
    }
    p4[it * 256 + threadIdx.x] = v;
  }
  for (int off = 32; off; off >>= 1) lsum += __shfl_xor(lsum, off);
  __shared__ float sl[4];
  if ((threadIdx.x & 63) == 0) sl[threadIdx.x >> 6] = lsum;
  __syncthreads();
  if (threadIdx.x == 0) omean[bc] = (sl[0] + sl[1] + sl[2] + sl[3]) * (1.0f / NPIX);
}

__global__ __launch_bounds__(256) void k_final(const float* __restrict__ b2,
                                               const float* __restrict__ b3,
                                               const float* __restrict__ s2s,
                                               const float* __restrict__ s2q,
                                               const float* __restrict__ s3s,
                                               const float* __restrict__ s3q,
                                               float* __restrict__ out) {
  int bc = blockIdx.x;
  float m2 = s2s[bc] * (1.0f / NPIX);
  float v2 = s2q[bc] * (1.0f / NPIX) - m2 * m2;
  float r2 = rsqrtf(v2 + 1e-5f);
  float m3 = s3s[bc] * (1.0f / NPIX);
  float v3 = s3q[bc] * (1.0f / NPIX) - m3 * m3;
  float r3 = rsqrtf(v3 + 1e-5f);
  const float4* p2 = (const float4*)(b2 + (size_t)bc * NPIX);
  const float4* p3 = (const float4*)(b3 + (size_t)bc * NPIX);
  float4* po = (float4*)(out + (size_t)bc * NPIX);
#pragma unroll
  for (int it = 0; it < 9; ++it) {
    float4 a = p2[it * 256 + threadIdx.x];
    float4 c = p3[it * 256 + threadIdx.x];
    float* aa = (float*)&a;
    float* ccp = (float*)&c;
#pragma unroll
    for (int u = 0; u < 4; ++u) {
      float x = (aa[u] - m2) * r2 + (ccp[u] - m3) * r3;
      aa[u] = (x >= 0.f) ? x : 0.01f * x;
    }
    po[it * 256 + threadIdx.x] = a;
  }
}

// ---------------------------------------------------------------------------
extern "C" void kernel_launch(void* const* d_in, const int* in_sizes, int n_in,
                              void* d_out, int out_size, void* d_ws, size_t ws_size,
                              hipStream_t stream) {
  const float* inp  = (const float*)d_in[0];
  const float* skip = (const float*)d_in[1];
  const float* wt   = (const float*)d_in[2];
  const float* c1w  = (const float*)d_in[3];
  const float* Wg1  = (const float*)d_in[4];
  const float* bg1  = (const float*)d_in[5];
  const float* A1   = (const float*)d_in[6];
  const float* c2w  = (const float*)d_in[7];
  const float* Wg2  = (const float*)d_in[8];
  const float* bg2  = (const float*)d_in[9];
  const float* A2   = (const float*)d_in[10];
  const float* c3w  = (const float*)d_in[11];
  const float* Wg3  = (const float*)d_in[12];
  const float* bg3  = (const float*)d_in[13];
  const float* A3   = (const float*)d_in[14];

  float* ws = (float*)d_ws;
  float* UP    = ws + OFF_UP;
  float* BUF1  = ws + OFF_BUF1;
  float* BUF2  = ws + OFF_BUF2;   // aliases UP (dead by conv2)
  float* BUF3  = ws + OFF_BUF3;
  float* WMIX1 = ws + OFF_WMIX1;
  float* WRES  = ws + OFF_WRES;
  float* WMIX2 = ws + OFF_WMIX2;
  float* XMEAN = ws + OFF_XMEAN;
  float* O1M   = ws + OFF_O1M;
  float* G1    = ws + OFF_G1;
  float* G2    = ws + OFF_G2;
  float* G3    = ws + OFF_G3;
  float* S1S = ws + OFF_STATS;
  float* S1Q = S1S + 2048;
  float* S2S = S1Q + 2048;
  float* S2Q = S2S + 2048;
  float* S3S = S2Q + 2048;
  float* S3Q = S3S + 2048;

  hipMemsetAsync(S1S, 0, 6 * 2048 * sizeof(float), stream);

  k_up<<<dim3(72, NB), 256, 0, stream>>>(inp, wt, UP);
  k_colmean<<<NB * C2, 256, 0, stream>>>(UP, skip, XMEAN);
  k_gate<<<NB, 256, 0, stream>>>(XMEAN, C2, Wg1, bg1, G1);
  k_gate<<<NB, 256, 0, stream>>>(XMEAN, C2, Wg3, bg3, G3);
  k_mixw13<<<2048, 256, 0, stream>>>(A1, A3, c3w, G1, G3, WMIX1, WRES);
  k_conv<256, true><<<dim3(18, 4, NB), 256, 0, stream>>>(UP, skip, c1w, WMIX1, BUF1, S1S, S1Q);
  k_conv<256, false><<<dim3(18, 4, NB), 256, 0, stream>>>(UP, skip, nullptr, WRES, BUF3, S3S, S3Q);
  k_norm1<<<NB * C1, 256, 0, stream>>>(BUF1, S1S, S1Q, O1M);
  k_gate<<<NB, 256, 0, stream>>>(O1M, C1, Wg2, bg2, G2);
  k_mixw2<<<1024, 256, 0, stream>>>(A2, G2, WMIX2);
  k_conv<128, true><<<dim3(18, 4, NB), 256, 0, stream>>>(BUF1, nullptr, c2w, WMIX2, BUF2, S2S, S2Q);
  k_final<<<NB * C1, 256, 0, stream>>>(BUF2, BUF3, S2S, S2Q, S3S, S3Q, (float*)d_out);
}

// Round 6
// 739.682 us; speedup vs baseline: 4.9991x; 4.9991x over previous
//
#include <hip/hip_runtime.h>

// ---------------------------------------------------------------------------
// UnetrUpBlockSLA — r5 (= r2 resubmit, 4th attempt): MFMA fp16 convs.
//   k_up     : fp32 ConvTranspose2d (unchanged)          -> A (=UP, NCHW f32)
//   k_cvt1   : UP+skip -> XT NHWC fp16 + XSUM (gate means)
//   k_gate   : sparsemax gates g1,g3 (later g2)
//   k_fold   : per-sample weights, mix folded into center tap, fp16,
//              layout [b][chunk][tap][cig4][o128][e8]
//   k_cgemm  : implicit-GEMM conv via mfma_f32_16x16x32_f16,
//              128o x 8r x 48c block, 8 waves, Fm=4 Fn=6; fused IN stats
//   k_norm1x : lrelu(instnorm(BUF1)) -> XT2 NHWC fp16 + O1SUM
//   k_final  : lrelu(IN(BUF2)+IN(BUF3))
// Aliasing: A = UP/BUF1/BUF2 ; XT2 = XT ; W2F = W1F ; BUF3 fp16. ws = 199 MB.
// ---------------------------------------------------------------------------

#define NB   16
#define C2   256
#define C1   128
#define HO   96
#define WO   96
#define NPIX 9216
#define HI   48
#define WI   48

typedef _Float16 f16;
typedef __attribute__((ext_vector_type(8))) _Float16 f16x8;
typedef __attribute__((ext_vector_type(4))) _Float16 f16x4;
typedef __attribute__((ext_vector_type(4))) float f32x4;

// workspace offsets in fp32 words
#define OFF_A     0ull           // 18,874,368 w  (UP / BUF1 / BUF2, f32 NCHW)
#define OFF_B3    18874368ull    //  9,437,184 w  (BUF3 fp16 NCHW)
#define OFF_XT    28311552ull    // 18,874,368 w  (XT fp16 NHWC; XT2 aliases)
#define OFF_W1F   47185920ull    //  2,359,296 w  (W1F fp16; W2F aliases)
#define OFF_WRF   49545216ull    //    262,144 w
#define OFF_XSUM  49807360ull    // 4096
#define OFF_O1SUM 49811456ull    // 2048
#define OFF_G1    49813504ull
#define OFF_G2    49813568ull
#define OFF_G3    49813632ull
#define OFF_STATS 49813696ull    // 6*2048

// ---------------------------------------------------------------------------
// fp32 transposed conv 2x2 s2 (unchanged from r1; correct, ~5% of FLOPs)
__global__ __launch_bounds__(256) void k_up(const float* __restrict__ inp,
                                            const float* __restrict__ wt,
                                            float* __restrict__ up) {
  int b = blockIdx.y;
  int oc = blockIdx.x & 7;
  int tile = blockIdx.x >> 3;
  int i0 = (tile / 3) * 16, j0 = (tile % 3) * 16;
  int t = threadIdx.x;
  int og = t >> 6, pg = t & 63, pi = pg >> 2, pj4 = pg & 3;

  __shared__ float  s_in[16 * 272];
  __shared__ float4 s_w4[256];

  float4 acc[4][4];
#pragma unroll
  for (int j = 0; j < 4; j++)
#pragma unroll
    for (int oo = 0; oo < 4; oo++) acc[j][oo] = make_float4(0.f, 0.f, 0.f, 0.f);

  for (int cc = 0; cc < 16; ++cc) {
#pragma unroll
    for (int it = 0; it < 16; ++it) {
      int flat = it * 256 + t;
      int ci = flat >> 8, i = (flat >> 4) & 15, j = flat & 15;
      s_in[ci * 272 + i * 17 + j] =
          inp[((size_t)(b * C2 + cc * 16 + ci) * HI + (i0 + i)) * WI + (j0 + j)];
    }
    {
      int ci = t >> 4, o = t & 15;
      s_w4[ci * 16 + o] = ((const float4*)wt)[(size_t)(cc * 16 + ci) * C1 + oc * 16 + o];
    }
    __syncthreads();
#pragma unroll
    for (int ci = 0; ci < 16; ++ci) {
      float iv[4];
#pragma unroll
      for (int q = 0; q < 4; q++) iv[q] = s_in[ci * 272 + pi * 17 + pj4 * 4 + q];
#pragma unroll
      for (int oo = 0; oo < 4; oo++) {
        float4 w = s_w4[ci * 16 + og * 4 + oo];
#pragma unroll
        for (int j = 0; j < 4; j++) {
          acc[j][oo].x += iv[j] * w.x; acc[j][oo].y += iv[j] * w.y;
          acc[j][oo].z += iv[j] * w.z; acc[j][oo].w += iv[j] * w.w;
        }
      }
    }
    __syncthreads();
  }
  int orow = 2 * (i0 + pi);
#pragma unroll
  for (int oo = 0; oo < 4; oo++) {
    int o = oc * 16 + og * 4 + oo;
    float* base = up + (size_t)(b * C1 + o) * HO * WO;
#pragma unroll
    for (int j = 0; j < 4; j++) {
      int jj = j0 + pj4 * 4 + j;
      *(float2*)(base + (size_t)orow * WO + 2 * jj)       = make_float2(acc[j][oo].x, acc[j][oo].y);
      *(float2*)(base + (size_t)(orow + 1) * WO + 2 * jj) = make_float2(acc[j][oo].z, acc[j][oo].w);
    }
  }
}

// ---------------------------------------------------------------------------
// UP + skip (f32 NCHW) -> XT (fp16 NHWC [b][r][c][256]) + per-(b,c) sums
__global__ __launch_bounds__(256) void k_cvt1(const float* __restrict__ up,
                                              const float* __restrict__ skip,
                                              f16* __restrict__ xt,
                                              float* __restrict__ xsum) {
  int b = blockIdx.y, r = blockIdx.x;
  int c = threadIdx.x;
  __shared__ f16 slab[96 * 256];
  const float* src = (c < C1) ? up + ((size_t)(b * C1 + c) * HO + r) * WO
                              : skip + ((size_t)(b * C1 + (c - C1)) * HO + r) * WO;
  float sum = 0.f;
#pragma unroll
  for (int j = 0; j < 96; j += 4) {
    float4 v = *(const float4*)(src + j);
    slab[(j + 0) * 256 + c] = (f16)v.x;
    slab[(j + 1) * 256 + c] = (f16)v.y;
    slab[(j + 2) * 256 + c] = (f16)v.z;
    slab[(j + 3) * 256 + c] = (f16)v.w;
    sum += v.x + v.y + v.z + v.w;
  }
  atomicAdd(&xsum[b * 256 + c], sum);
  __syncthreads();
  uint4* dstv = (uint4*)(xt + (size_t)(b * 96 + r) * 96 * 256);
  const uint4* sv = (const uint4*)slab;
#pragma unroll
  for (int i = 0; i < 12; ++i) dstv[i * 256 + threadIdx.x] = sv[i * 256 + threadIdx.x];
}

// ---------------------------------------------------------------------------
// gates: z = (xsum*scale)@Wg^T + bg ; sparsemax K=4
__global__ __launch_bounds__(256) void k_gate(const float* __restrict__ xs, int CI,
                                              float scale,
                                              const float* __restrict__ Wg,
                                              const float* __restrict__ bg,
                                              float* __restrict__ g) {
  int b = blockIdx.x;
  int w = threadIdx.x >> 6, lane = threadIdx.x & 63;
  float sum = 0.f;
  for (int i = lane; i < CI; i += 64) sum += xs[b * CI + i] * Wg[w * CI + i];
  for (int off = 32; off; off >>= 1) sum += __shfl_xor(sum, off);
  __shared__ float z[4];
  if (lane == 0) z[w] = sum * scale + bg[w];
  __syncthreads();
  if (threadIdx.x == 0) {
    float zz[4] = {z[0], z[1], z[2], z[3]};
    float a0 = zz[0], a1 = zz[1], a2 = zz[2], a3 = zz[3], tmp;
    if (a0 < a1) { tmp = a0; a0 = a1; a1 = tmp; }
    if (a2 < a3) { tmp = a2; a2 = a3; a3 = tmp; }
    if (a0 < a2) { tmp = a0; a0 = a2; a2 = tmp; }
    if (a1 < a3) { tmp = a1; a1 = a3; a3 = tmp; }
    if (a1 < a2) { tmp = a1; a1 = a2; a2 = tmp; }
    float cs0 = a0, cs1 = cs0 + a1, cs2 = cs1 + a2, cs3 = cs2 + a3;
    int km = (1.f + 1.f * a0 > cs0) + (1.f + 2.f * a1 > cs1) +
             (1.f + 3.f * a2 > cs2) + (1.f + 4.f * a3 > cs3);
    float csk = (km == 1) ? cs0 : (km == 2) ? cs1 : (km == 3) ? cs2 : cs3;
    float tau = (csk - 1.f) / (float)km;
#pragma unroll
    for (int k = 0; k < 4; k++) g[b * 4 + k] = fmaxf(zz[k] - tau, 0.f);
  }
}

// ---------------------------------------------------------------------------
// fold per-sample weights to fp16, layout [b][ch][tap][cig4][o128][e8]
// 3x3: wv = convw[o][ci][tap] (+ mix at tap 4) ; 1x1: wv = convw[o][ci] + mix
template <int CI, int NT, bool IS1X1>
__global__ __launch_bounds__(256) void k_fold(const float* __restrict__ convw,
                                              const float* __restrict__ Amat,
                                              const float* __restrict__ gate,
                                              f16* __restrict__ wf) {
  constexpr int NCH = CI / 32;
  int g = blockIdx.x * 256 + threadIdx.x;
  int o = g & 127;
  int cig = (g >> 7) & 3;
  int rest = g >> 9;
  int tap = rest % NT;
  int rest2 = rest / NT;
  int ch = rest2 % NCH;
  int b = rest2 / NCH;
  int ci0 = ch * 32 + cig * 8;

  float gk[4];
#pragma unroll
  for (int k = 0; k < 4; k++) gk[k] = gate[b * 4 + k];

  f16 out8[8];
#pragma unroll
  for (int e = 0; e < 8; ++e) {
    int ci = ci0 + e;
    float wv;
    if (IS1X1) wv = convw[(size_t)o * CI + ci];
    else       wv = convw[((size_t)o * CI + ci) * 9 + tap];
    if (IS1X1 || tap == 4) {
#pragma unroll
      for (int k = 0; k < 4; k++) wv += gk[k] * Amat[((size_t)k * C1 + o) * CI + ci];
    }
    out8[e] = (f16)wv;
  }
  *(uint4*)(wf + (size_t)g * 8) = *(const uint4*)out8;
}

// ---------------------------------------------------------------------------
// Implicit-GEMM conv via MFMA. Block = 128 o x (8 rows x 48 cols), 8 waves.
// Wave: mh = w>>2 (64 o), nq = w&3 (2 rows). Fm=4, Fn=6 (2r x 3 c16).
// LDS x: [cig4][r10][c50][e8] fp16 (granule-split: B-frag reads conflict-free)
// LDS w: [cig4][o128][e8], cig stride padded to 129 granules (A-frag c-free)
template <int CI, bool HALO, bool HALF_OUT>
__global__ __launch_bounds__(512, 2) void k_cgemm(const f16* __restrict__ xt,
                                                  const f16* __restrict__ wf,
                                                  float* __restrict__ dst,
                                                  f16* __restrict__ dsth,
                                                  float* __restrict__ ssum,
                                                  float* __restrict__ ssq) {
  constexpr int NT = HALO ? 9 : 1;
  constexpr int NCH = CI / 32;
  int b = blockIdx.z;
  int rt = blockIdx.x >> 1, ct = blockIdx.x & 1;
  int r0 = rt * 8, c0 = ct * 48;
  int tid = threadIdx.x;
  int w = tid >> 6, l = tid & 63;
  int mh = w >> 2, nq = w & 3;
  int o0w = mh * 64;
  int l15 = l & 15, l4 = l >> 4;

  __shared__ __align__(16) f16 sx[4 * 10 * 50 * 8];   // 32 KB
  __shared__ __align__(16) f16 sw[2][4 * 129 * 8];    // 2 x 8.25 KB (padded)

  f32x4 acc[4][6];
#pragma unroll
  for (int mf = 0; mf < 4; ++mf)
#pragma unroll
    for (int nf = 0; nf < 6; ++nf) acc[mf][nf] = (f32x4){0.f, 0.f, 0.f, 0.f};

  int buf = 0;
  for (int ch = 0; ch < NCH; ++ch) {
    // ---- stage x chunk (32 ci) ----
    if (HALO) {
      for (int flat = tid; flat < 2000; flat += 512) {
        int cig = flat & 3, pos = flat >> 2;
        int rr = pos / 50, cc = pos % 50;
        int gr = r0 - 1 + rr, gc = c0 - 1 + cc;
        uint4 v = make_uint4(0u, 0u, 0u, 0u);
        if (gr >= 0 && gr < 96 && gc >= 0 && gc < 96)
          v = *(const uint4*)(xt + ((size_t)(b * 96 + gr) * 96 + gc) * CI + ch * 32 + cig * 8);
        *(uint4*)(sx + ((cig * 10 + rr) * 50 + cc) * 8) = v;
      }
    } else {
      for (int flat = tid; flat < 1536; flat += 512) {
        int cig = flat & 3, pos = flat >> 2;
        int rr = 1 + pos / 48, cc = 1 + pos % 48;
        int gr = r0 + pos / 48, gc = c0 + pos % 48;
        uint4 v = *(const uint4*)(xt + ((size_t)(b * 96 + gr) * 96 + gc) * CI + ch * 32 + cig * 8);
        *(uint4*)(sx + ((cig * 10 + rr) * 50 + cc) * 8) = v;
      }
    }
    // ---- stage w tap 0 ----
    {
      const f16* src = wf + ((size_t)(b * NCH + ch) * NT + 0) * 4096;
      int cig = tid >> 7, o = tid & 127;
      *(uint4*)(sw[buf] + (cig * 129 + o) * 8) = *(const uint4*)(src + tid * 8);
    }
    __syncthreads();
    for (int tap = 0; tap < NT; ++tap) {
      if (tap + 1 < NT) {
        const f16* src = wf + ((size_t)(b * NCH + ch) * NT + tap + 1) * 4096;
        int cig = tid >> 7, o = tid & 127;
        *(uint4*)(sw[buf ^ 1] + (cig * 129 + o) * 8) = *(const uint4*)(src + tid * 8);
      }
      int dr = HALO ? tap / 3 : 1, dc = HALO ? tap % 3 : 1;
      f16x8 af[4];
#pragma unroll
      for (int mf = 0; mf < 4; ++mf)
        af[mf] = *(const f16x8*)(sw[buf] + (l4 * 129 + o0w + mf * 16 + l15) * 8);
      f16x8 bf[6];
#pragma unroll
      for (int rr2 = 0; rr2 < 2; ++rr2)
#pragma unroll
        for (int c16 = 0; c16 < 3; ++c16) {
          int lr = nq * 2 + rr2 + dr;
          int lc = c16 * 16 + l15 + dc;
          bf[rr2 * 3 + c16] = *(const f16x8*)(sx + ((l4 * 10 + lr) * 50 + lc) * 8);
        }
#pragma unroll
      for (int mf = 0; mf < 4; ++mf)
#pragma unroll
        for (int nf = 0; nf < 6; ++nf)
          acc[mf][nf] = __builtin_amdgcn_mfma_f32_16x16x32_f16(af[mf], bf[nf], acc[mf][nf], 0, 0, 0);
      __syncthreads();
      buf ^= 1;
    }
  }

  // ---- epilogue: write + fused IN stats ----
#pragma unroll
  for (int mf = 0; mf < 4; ++mf) {
#pragma unroll
    for (int reg = 0; reg < 4; ++reg) {
      int o = o0w + mf * 16 + l4 * 4 + reg;
      float s = 0.f, q = 0.f;
#pragma unroll
      for (int nf = 0; nf < 6; ++nf) {
        int rr2 = nf / 3, c16 = nf % 3;
        float v = acc[mf][nf][reg];
        int gr = r0 + nq * 2 + rr2, gc = c0 + c16 * 16 + l15;
        size_t off = ((size_t)(b * C1 + o) * 96 + gr) * 96 + gc;
        if (HALF_OUT) dsth[off] = (f16)v; else dst[off] = v;
        s += v; q += v * v;
      }
#pragma unroll
      for (int m = 1; m < 16; m <<= 1) { s += __shfl_xor(s, m); q += __shfl_xor(q, m); }
      if (l15 == 0) {
        atomicAdd(&ssum[b * C1 + o], s);
        atomicAdd(&ssq[b * C1 + o], q);
      }
    }
  }
}

// ---------------------------------------------------------------------------
// BUF1 f32 NCHW + stats -> lrelu(instnorm) -> XT2 fp16 NHWC [b][r][c][128] + O1SUM
__global__ __launch_bounds__(256) void k_norm1x(const float* __restrict__ buf,
                                                const float* __restrict__ ssum,
                                                const float* __restrict__ ssq,
                                                f16* __restrict__ xt2,
                                                float* __restrict__ osum) {
  int b = blockIdx.y, r = blockIdx.x;
  __shared__ f16 slab[96 * 128];
  __shared__ float mtab[128], rtab[128];
  int t = threadIdx.x;
  if (t < 128) {
    float m = ssum[b * C1 + t] * (1.0f / NPIX);
    float v = ssq[b * C1 + t] * (1.0f / NPIX) - m * m;
    mtab[t] = m; rtab[t] = rsqrtf(v + 1e-5f);
  }
  __syncthreads();
  int c = t & 127, half = t >> 7;
  const float* src = buf + ((size_t)(b * C1 + c) * HO + r) * WO + half * 48;
  float m = mtab[c], ri = rtab[c], sum = 0.f;
#pragma unroll
  for (int j = 0; j < 48; j += 4) {
    float4 v = *(const float4*)(src + j);
    float x0 = (v.x - m) * ri; x0 = x0 >= 0.f ? x0 : 0.01f * x0;
    float x1 = (v.y - m) * ri; x1 = x1 >= 0.f ? x1 : 0.01f * x1;
    float x2 = (v.z - m) * ri; x2 = x2 >= 0.f ? x2 : 0.01f * x2;
    float x3 = (v.w - m) * ri; x3 = x3 >= 0.f ? x3 : 0.01f * x3;
    slab[(half * 48 + j + 0) * 128 + c] = (f16)x0;
    slab[(half * 48 + j + 1) * 128 + c] = (f16)x1;
    slab[(half * 48 + j + 2) * 128 + c] = (f16)x2;
    slab[(half * 48 + j + 3) * 128 + c] = (f16)x3;
    sum += x0 + x1 + x2 + x3;
  }
  atomicAdd(&osum[b * C1 + c], sum);
  __syncthreads();
  uint4* dstv = (uint4*)(xt2 + (size_t)(b * 96 + r) * 96 * 128);
  const uint4* sv = (const uint4*)slab;
#pragma unroll
  for (int i = 0; i < 6; ++i) dstv[i * 256 + t] = sv[i * 256 + t];
}

// ---------------------------------------------------------------------------
__global__ __launch_bounds__(256) void k_final(const float* __restrict__ b2,
                                               const f16* __restrict__ b3,
                                               const float* __restrict__ s2s,
                                               const float* __restrict__ s2q,
                                               const float* __restrict__ s3s,
                                               const float* __restrict__ s3q,
                                               float* __restrict__ out) {
  int bc = blockIdx.x;
  float m2 = s2s[bc] * (1.0f / NPIX);
  float v2 = s2q[bc] * (1.0f / NPIX) - m2 * m2;
  float r2 = rsqrtf(v2 + 1e-5f);
  float m3 = s3s[bc] * (1.0f / NPIX);
  float v3 = s3q[bc] * (1.0f / NPIX) - m3 * m3;
  float r3 = rsqrtf(v3 + 1e-5f);
  const float4* p2 = (const float4*)(b2 + (size_t)bc * NPIX);
  const f16x4* p3 = (const f16x4*)(b3 + (size_t)bc * NPIX);
  float4* po = (float4*)(out + (size_t)bc * NPIX);
#pragma unroll
  for (int it = 0; it < 9; ++it) {
    float4 a = p2[it * 256 + threadIdx.x];
    f16x4 c = p3[it * 256 + threadIdx.x];
    float* aa = (float*)&a;
#pragma unroll
    for (int u = 0; u < 4; ++u) {
      float x = (aa[u] - m2) * r2 + ((float)c[u] - m3) * r3;
      aa[u] = (x >= 0.f) ? x : 0.01f * x;
    }
    po[it * 256 + threadIdx.x] = a;
  }
}

// ---------------------------------------------------------------------------
extern "C" void kernel_launch(void* const* d_in, const int* in_sizes, int n_in,
                              void* d_out, int out_size, void* d_ws, size_t ws_size,
                              hipStream_t stream) {
  const float* inp  = (const float*)d_in[0];
  const float* skip = (const float*)d_in[1];
  const float* wt   = (const float*)d_in[2];
  const float* c1w  = (const float*)d_in[3];
  const float* Wg1  = (const float*)d_in[4];
  const float* bg1  = (const float*)d_in[5];
  const float* A1   = (const float*)d_in[6];
  const float* c2w  = (const float*)d_in[7];
  const float* Wg2  = (const float*)d_in[8];
  const float* bg2  = (const float*)d_in[9];
  const float* A2   = (const float*)d_in[10];
  const float* c3w  = (const float*)d_in[11];
  const float* Wg3  = (const float*)d_in[12];
  const float* bg3  = (const float*)d_in[13];
  const float* A3   = (const float*)d_in[14];

  float* ws = (float*)d_ws;
  float* A    = ws + OFF_A;            // UP -> BUF1 -> BUF2
  f16*  B3h   = (f16*)(ws + OFF_B3);
  f16*  XT    = (f16*)(ws + OFF_XT);   // XT2 aliases
  f16*  W1F   = (f16*)(ws + OFF_W1F);  // W2F aliases
  f16*  WRF   = (f16*)(ws + OFF_WRF);
  float* XSUM = ws + OFF_XSUM;
  float* O1S  = ws + OFF_O1SUM;
  float* G1   = ws + OFF_G1;
  float* G2   = ws + OFF_G2;
  float* G3   = ws + OFF_G3;
  float* S1S = ws + OFF_STATS;
  float* S1Q = S1S + 2048;
  float* S2S = S1Q + 2048;
  float* S2Q = S2S + 2048;
  float* S3S = S2Q + 2048;
  float* S3Q = S3S + 2048;

  hipMemsetAsync(XSUM, 0, (4096 + 2048 + 192 + 12288) * sizeof(float), stream);

  k_up<<<dim3(72, NB), 256, 0, stream>>>(inp, wt, A);
  k_cvt1<<<dim3(96, NB), 256, 0, stream>>>(A, skip, XT, XSUM);
  k_gate<<<NB, 256, 0, stream>>>(XSUM, C2, 1.0f / NPIX, Wg1, bg1, G1);
  k_gate<<<NB, 256, 0, stream>>>(XSUM, C2, 1.0f / NPIX, Wg3, bg3, G3);
  k_fold<256, 9, false><<<2304, 256, 0, stream>>>(c1w, A1, G1, W1F);
  k_fold<256, 1, true><<<256, 256, 0, stream>>>(c3w, A3, G3, WRF);
  k_cgemm<256, true, false><<<dim3(24, 1, NB), 512, 0, stream>>>(XT, W1F, A, nullptr, S1S, S1Q);
  k_cgemm<256, false, true><<<dim3(24, 1, NB), 512, 0, stream>>>(XT, WRF, nullptr, B3h, S3S, S3Q);
  k_norm1x<<<dim3(96, NB), 256, 0, stream>>>(A, S1S, S1Q, XT, O1S);
  k_gate<<<NB, 256, 0, stream>>>(O1S, C1, 1.0f / NPIX, Wg2, bg2, G2);
  k_fold<128, 9, false><<<1152, 256, 0, stream>>>(c2w, A2, G2, W1F);
  k_cgemm<128, true, false><<<dim3(24, 1, NB), 512, 0, stream>>>(XT, W1F, A, nullptr, S2S, S2Q);
  k_final<<<NB * C1, 256, 0, stream>>>(A, B3h, S2S, S2Q, S3S, S3Q, (float*)d_out);
}

// Round 11
// 668.019 us; speedup vs baseline: 5.5354x; 1.1073x over previous
//
#include <hip/hip_runtime.h>

// ---------------------------------------------------------------------------
// UnetrUpBlockSLA — r11 (= r7 resubmit, 5th attempt): MFMA everywhere it matters.
//   k_foldup : wt f32 -> WUP fp16 [tap4][cigG32][o128][e8]
//   k_upT    : MFMA transposed-conv, writes XT NHWC fp16 ci[0,128) + XSUM
//   k_cvts   : skip f32 NCHW -> XT ci[128,256) + XSUM
//   k_gate   : sparsemax gates
//   k_fold   : per-sample conv weights (mix folded), fp16
//   k_cgemm  : implicit-GEMM 3x3 conv (conv1, conv2) + fused IN stats
//   k_rgemm  : flat 1x1 GEMM for res branch (no halo) + fused IN stats
//   k_norm1x : lrelu(instnorm(BUF1)) -> XT2 NHWC fp16 + O1SUM
//   k_final  : lrelu(IN(BUF2)+IN(BUF3))
// Aliasing: A = BUF1/BUF2 ; XT2 = XT ; W2F = W1F ; BUF3 fp16. ws = 199.6 MB.
// ---------------------------------------------------------------------------

#define NB   16
#define C2   256
#define C1   128
#define HO   96
#define WO   96
#define NPIX 9216
#define HI   48
#define WI   48

typedef _Float16 f16;
typedef __attribute__((ext_vector_type(8))) _Float16 f16x8;
typedef __attribute__((ext_vector_type(4))) _Float16 f16x4;
typedef __attribute__((ext_vector_type(4))) float f32x4;

// workspace offsets in fp32 words
#define OFF_A     0ull           // 18,874,368 w  (BUF1 / BUF2, f32 NCHW)
#define OFF_B3    18874368ull    //  9,437,184 w  (BUF3 fp16 NCHW)
#define OFF_XT    28311552ull    // 18,874,368 w  (XT fp16 NHWC; XT2 aliases)
#define OFF_W1F   47185920ull    //  2,359,296 w  (W1F fp16; W2F aliases)
#define OFF_WRF   49545216ull    //    262,144 w
#define OFF_WUP   49807360ull    //     65,536 w  (WUP fp16)
#define OFF_XSUM  49872896ull    // 4096
#define OFF_O1SUM 49876992ull    // 2048
#define OFF_G1    49879040ull
#define OFF_G2    49879104ull
#define OFF_G3    49879168ull
#define OFF_STATS 49879232ull    // 6*2048 -> end 49891520 w (199.57 MB)

// ---------------------------------------------------------------------------
// fold ConvT weights: WUP[tap][cigG][o][e] = wt[cigG*8+e][o][di][dj]
__global__ __launch_bounds__(256) void k_foldup(const float* __restrict__ wt,
                                                f16* __restrict__ wup) {
  int g8 = blockIdx.x * 256 + threadIdx.x;   // 0..16383
  int o = g8 & 127, cigG = (g8 >> 7) & 31, tap = g8 >> 12;
  f16 tmp[8];
#pragma unroll
  for (int e = 0; e < 8; ++e)
    tmp[e] = (f16)wt[((size_t)(cigG * 8 + e) * 128 + o) * 4 + tap];
  *(uint4*)(wup + (size_t)g8 * 8) = *(const uint4*)tmp;
}

// ---------------------------------------------------------------------------
// MFMA transposed conv 2x2 s2. Block: 4x24 input px tile, all 256 K, 128 o,
// 4 taps. 8 waves = (tap, o-half); Fm=4, Fn=6. Writes XT ci[0,128) + XSUM.
__global__ __launch_bounds__(512, 2) void k_upT(const float* __restrict__ inp,
                                                const f16* __restrict__ wup,
                                                f16* __restrict__ xt,
                                                float* __restrict__ xsum) {
  int b = blockIdx.y;
  int rt = blockIdx.x >> 1, ct = blockIdx.x & 1;
  int i0 = rt * 4, j0 = ct * 24;
  int tid = threadIdx.x;
  int w = tid >> 6, l = tid & 63;
  int t = w & 3, mh = w >> 2;
  int di = t >> 1, dj = t & 1;
  int o0w = mh * 64;
  int l15 = l & 15, l4 = l >> 4;

  __shared__ __align__(16) f16 sxU[4 * 96 * 8];        // 6 KB
  __shared__ __align__(16) f16 swU[4 * 4 * 128 * 8];   // 32 KB

  f32x4 acc[4][6];
#pragma unroll
  for (int mf = 0; mf < 4; ++mf)
#pragma unroll
    for (int nf = 0; nf < 6; ++nf) acc[mf][nf] = (f32x4){0.f, 0.f, 0.f, 0.f};

  for (int ch = 0; ch < 8; ++ch) {
    if (tid < 384) {
      int cig = tid / 96, px = tid % 96;
      int pi = px / 24, pj = px % 24;
      const float* sp = inp + ((size_t)(b * 256 + ch * 32 + cig * 8) * 48 + (i0 + pi)) * 48 + (j0 + pj);
      f16 tmp[8];
#pragma unroll
      for (int e = 0; e < 8; ++e) tmp[e] = (f16)sp[(size_t)e * 2304];
      *(uint4*)(sxU + (cig * 96 + px) * 8) = *(const uint4*)tmp;
    }
#pragma unroll
    for (int q = 0; q < 4; ++q) {
      int g = q * 512 + tid;
      int tap = g >> 9, rem = g & 511;
      int cigl = rem >> 7, o = rem & 127;
      *(uint4*)(swU + ((tap * 4 + cigl) * 128 + o) * 8) =
          *(const uint4*)(wup + (((size_t)tap * 32 + ch * 4 + cigl) * 128 + o) * 8);
    }
    __syncthreads();
    f16x8 af[4];
#pragma unroll
    for (int mf = 0; mf < 4; ++mf)
      af[mf] = *(const f16x8*)(swU + ((t * 4 + l4) * 128 + o0w + mf * 16 + l15) * 8);
    f16x8 bf[6];
#pragma unroll
    for (int nf = 0; nf < 6; ++nf)
      bf[nf] = *(const f16x8*)(sxU + (l4 * 96 + nf * 16 + l15) * 8);
#pragma unroll
    for (int mf = 0; mf < 4; ++mf)
#pragma unroll
      for (int nf = 0; nf < 6; ++nf)
        acc[mf][nf] = __builtin_amdgcn_mfma_f32_16x16x32_f16(af[mf], bf[nf], acc[mf][nf], 0, 0, 0);
    __syncthreads();
  }

  // epilogue: scatter to XT (8B stores, L2 merges) + XSUM
  float osum[4][4];
#pragma unroll
  for (int mf = 0; mf < 4; ++mf)
#pragma unroll
    for (int reg = 0; reg < 4; ++reg) osum[mf][reg] = 0.f;
#pragma unroll
  for (int mf = 0; mf < 4; ++mf) {
#pragma unroll
    for (int nf = 0; nf < 6; ++nf) {
      int px = nf * 16 + l15, pi = px / 24, pj = px % 24;
      int R = 2 * (i0 + pi) + di, CP = 2 * (j0 + pj) + dj;
      f16 hv[4];
#pragma unroll
      for (int reg = 0; reg < 4; ++reg) {
        float v = acc[mf][nf][reg];
        hv[reg] = (f16)v;
        osum[mf][reg] += v;
      }
      *(uint2*)(xt + ((size_t)(b * 96 + R) * 96 + CP) * 256 + o0w + mf * 16 + l4 * 4) = *(const uint2*)hv;
    }
  }
#pragma unroll
  for (int mf = 0; mf < 4; ++mf)
#pragma unroll
    for (int reg = 0; reg < 4; ++reg) {
      float s = osum[mf][reg];
#pragma unroll
      for (int m = 1; m < 16; m <<= 1) s += __shfl_xor(s, m);
      if (l15 == 0)
        atomicAdd(&xsum[b * 256 + o0w + mf * 16 + l4 * 4 + reg], s);
    }
}

// ---------------------------------------------------------------------------
// skip f32 NCHW -> XT ci[128,256) fp16 + XSUM
__global__ __launch_bounds__(256) void k_cvts(const float* __restrict__ skip,
                                              f16* __restrict__ xt,
                                              float* __restrict__ xsum) {
  int b = blockIdx.y, r = blockIdx.x;
  __shared__ f16 slab[96 * 128];
  int tthr = threadIdx.x;
  int c = tthr & 127, half = tthr >> 7;
  const float* src = skip + ((size_t)(b * C1 + c) * HO + r) * WO + half * 48;
  float sum = 0.f;
#pragma unroll
  for (int j = 0; j < 48; j += 4) {
    float4 v = *(const float4*)(src + j);
    slab[(half * 48 + j + 0) * 128 + c] = (f16)v.x;
    slab[(half * 48 + j + 1) * 128 + c] = (f16)v.y;
    slab[(half * 48 + j + 2) * 128 + c] = (f16)v.z;
    slab[(half * 48 + j + 3) * 128 + c] = (f16)v.w;
    sum += v.x + v.y + v.z + v.w;
  }
  atomicAdd(&xsum[b * 256 + 128 + c], sum);
  __syncthreads();
  const uint4* sv = (const uint4*)slab;
  for (int flat = tthr; flat < 1536; flat += 256) {
    int px = flat >> 4, u = flat & 15;
    *(uint4*)(xt + ((size_t)(b * 96 + r) * 96 + px) * 256 + 128 + u * 8) = sv[flat];
  }
}

// ---------------------------------------------------------------------------
// gates: z = (xsum*scale)@Wg^T + bg ; sparsemax K=4
__global__ __launch_bounds__(256) void k_gate(const float* __restrict__ xs, int CI,
                                              float scale,
                                              const float* __restrict__ Wg,
                                              const float* __restrict__ bg,
                                              float* __restrict__ g) {
  int b = blockIdx.x;
  int w = threadIdx.x >> 6, lane = threadIdx.x & 63;
  float sum = 0.f;
  for (int i = lane; i < CI; i += 64) sum += xs[b * CI + i] * Wg[w * CI + i];
  for (int off = 32; off; off >>= 1) sum += __shfl_xor(sum, off);
  __shared__ float z[4];
  if (lane == 0) z[w] = sum * scale + bg[w];
  __syncthreads();
  if (threadIdx.x == 0) {
    float zz[4] = {z[0], z[1], z[2], z[3]};
    float a0 = zz[0], a1 = zz[1], a2 = zz[2], a3 = zz[3], tmp;
    if (a0 < a1) { tmp = a0; a0 = a1; a1 = tmp; }
    if (a2 < a3) { tmp = a2; a2 = a3; a3 = tmp; }
    if (a0 < a2) { tmp = a0; a0 = a2; a2 = tmp; }
    if (a1 < a3) { tmp = a1; a1 = a3; a3 = tmp; }
    if (a1 < a2) { tmp = a1; a1 = a2; a2 = tmp; }
    float cs0 = a0, cs1 = cs0 + a1, cs2 = cs1 + a2, cs3 = cs2 + a3;
    int km = (1.f + 1.f * a0 > cs0) + (1.f + 2.f * a1 > cs1) +
             (1.f + 3.f * a2 > cs2) + (1.f + 4.f * a3 > cs3);
    float csk = (km == 1) ? cs0 : (km == 2) ? cs1 : (km == 3) ? cs2 : cs3;
    float tau = (csk - 1.f) / (float)km;
#pragma unroll
    for (int k = 0; k < 4; k++) g[b * 4 + k] = fmaxf(zz[k] - tau, 0.f);
  }
}

// ---------------------------------------------------------------------------
// fold per-sample weights to fp16, layout [b][ch][tap][cig4][o128][e8]
template <int CI, int NT, bool IS1X1>
__global__ __launch_bounds__(256) void k_fold(const float* __restrict__ convw,
                                              const float* __restrict__ Amat,
                                              const float* __restrict__ gate,
                                              f16* __restrict__ wf) {
  constexpr int NCH = CI / 32;
  int g = blockIdx.x * 256 + threadIdx.x;
  int o = g & 127;
  int cig = (g >> 7) & 3;
  int rest = g >> 9;
  int tap = rest % NT;
  int rest2 = rest / NT;
  int ch = rest2 % NCH;
  int b = rest2 / NCH;
  int ci0 = ch * 32 + cig * 8;

  float gk[4];
#pragma unroll
  for (int k = 0; k < 4; k++) gk[k] = gate[b * 4 + k];

  f16 out8[8];
#pragma unroll
  for (int e = 0; e < 8; ++e) {
    int ci = ci0 + e;
    float wv;
    if (IS1X1) wv = convw[(size_t)o * CI + ci];
    else       wv = convw[((size_t)o * CI + ci) * 9 + tap];
    if (IS1X1 || tap == 4) {
#pragma unroll
      for (int k = 0; k < 4; k++) wv += gk[k] * Amat[((size_t)k * C1 + o) * CI + ci];
    }
    out8[e] = (f16)wv;
  }
  *(uint4*)(wf + (size_t)g * 8) = *(const uint4*)out8;
}

// ---------------------------------------------------------------------------
// Implicit-GEMM 3x3 conv via MFMA (validated r5).
template <int CI, bool HALO, bool HALF_OUT>
__global__ __launch_bounds__(512, 2) void k_cgemm(const f16* __restrict__ xt,
                                                  const f16* __restrict__ wf,
                                                  float* __restrict__ dst,
                                                  f16* __restrict__ dsth,
                                                  float* __restrict__ ssum,
                                                  float* __restrict__ ssq) {
  constexpr int NT = HALO ? 9 : 1;
  constexpr int NCH = CI / 32;
  int b = blockIdx.z;
  int rt = blockIdx.x >> 1, ct = blockIdx.x & 1;
  int r0 = rt * 8, c0 = ct * 48;
  int tid = threadIdx.x;
  int w = tid >> 6, l = tid & 63;
  int mh = w >> 2, nq = w & 3;
  int o0w = mh * 64;
  int l15 = l & 15, l4 = l >> 4;

  __shared__ __align__(16) f16 sx[4 * 10 * 50 * 8];   // 32 KB
  __shared__ __align__(16) f16 sw[2][4 * 129 * 8];    // 2 x 8.25 KB

  f32x4 acc[4][6];
#pragma unroll
  for (int mf = 0; mf < 4; ++mf)
#pragma unroll
    for (int nf = 0; nf < 6; ++nf) acc[mf][nf] = (f32x4){0.f, 0.f, 0.f, 0.f};

  int buf = 0;
  for (int ch = 0; ch < NCH; ++ch) {
    if (HALO) {
      for (int flat = tid; flat < 2000; flat += 512) {
        int cig = flat & 3, pos = flat >> 2;
        int rr = pos / 50, cc = pos % 50;
        int gr = r0 - 1 + rr, gc = c0 - 1 + cc;
        uint4 v = make_uint4(0u, 0u, 0u, 0u);
        if (gr >= 0 && gr < 96 && gc >= 0 && gc < 96)
          v = *(const uint4*)(xt + ((size_t)(b * 96 + gr) * 96 + gc) * CI + ch * 32 + cig * 8);
        *(uint4*)(sx + ((cig * 10 + rr) * 50 + cc) * 8) = v;
      }
    } else {
      for (int flat = tid; flat < 1536; flat += 512) {
        int cig = flat & 3, pos = flat >> 2;
        int rr = 1 + pos / 48, cc = 1 + pos % 48;
        int gr = r0 + pos / 48, gc = c0 + pos % 48;
        uint4 v = *(const uint4*)(xt + ((size_t)(b * 96 + gr) * 96 + gc) * CI + ch * 32 + cig * 8);
        *(uint4*)(sx + ((cig * 10 + rr) * 50 + cc) * 8) = v;
      }
    }
    {
      const f16* src = wf + ((size_t)(b * NCH + ch) * NT + 0) * 4096;
      int cig = tid >> 7, o = tid & 127;
      *(uint4*)(sw[buf] + (cig * 129 + o) * 8) = *(const uint4*)(src + tid * 8);
    }
    __syncthreads();
    for (int tap = 0; tap < NT; ++tap) {
      if (tap + 1 < NT) {
        const f16* src = wf + ((size_t)(b * NCH + ch) * NT + tap + 1) * 4096;
        int cig = tid >> 7, o = tid & 127;
        *(uint4*)(sw[buf ^ 1] + (cig * 129 + o) * 8) = *(const uint4*)(src + tid * 8);
      }
      int dr = HALO ? tap / 3 : 1, dc = HALO ? tap % 3 : 1;
      f16x8 af[4];
#pragma unroll
      for (int mf = 0; mf < 4; ++mf)
        af[mf] = *(const f16x8*)(sw[buf] + (l4 * 129 + o0w + mf * 16 + l15) * 8);
      f16x8 bf[6];
#pragma unroll
      for (int rr2 = 0; rr2 < 2; ++rr2)
#pragma unroll
        for (int c16 = 0; c16 < 3; ++c16) {
          int lr = nq * 2 + rr2 + dr;
          int lc = c16 * 16 + l15 + dc;
          bf[rr2 * 3 + c16] = *(const f16x8*)(sx + ((l4 * 10 + lr) * 50 + lc) * 8);
        }
#pragma unroll
      for (int mf = 0; mf < 4; ++mf)
#pragma unroll
        for (int nf = 0; nf < 6; ++nf)
          acc[mf][nf] = __builtin_amdgcn_mfma_f32_16x16x32_f16(af[mf], bf[nf], acc[mf][nf], 0, 0, 0);
      __syncthreads();
      buf ^= 1;
    }
  }

#pragma unroll
  for (int mf = 0; mf < 4; ++mf) {
#pragma unroll
    for (int reg = 0; reg < 4; ++reg) {
      int o = o0w + mf * 16 + l4 * 4 + reg;
      float s = 0.f, q = 0.f;
#pragma unroll
      for (int nf = 0; nf < 6; ++nf) {
        int rr2 = nf / 3, c16 = nf % 3;
        float v = acc[mf][nf][reg];
        int gr = r0 + nq * 2 + rr2, gc = c0 + c16 * 16 + l15;
        size_t off = ((size_t)(b * C1 + o) * 96 + gr) * 96 + gc;
        if (HALF_OUT) dsth[off] = (f16)v; else dst[off] = v;
        s += v; q += v * v;
      }
#pragma unroll
      for (int m = 1; m < 16; m <<= 1) { s += __shfl_xor(s, m); q += __shfl_xor(q, m); }
      if (l15 == 0) {
        atomicAdd(&ssum[b * C1 + o], s);
        atomicAdd(&ssq[b * C1 + o], q);
      }
    }
  }
}

// ---------------------------------------------------------------------------
// Flat 1x1 GEMM for res branch: no halo, 2x96 px tile, XT read exactly once.
__global__ __launch_bounds__(512, 2) void k_rgemm(const f16* __restrict__ xt,
                                                  const f16* __restrict__ wrf,
                                                  f16* __restrict__ dsth,
                                                  float* __restrict__ ssum,
                                                  float* __restrict__ ssq) {
  int b = blockIdx.y;
  int r0 = blockIdx.x * 2;
  int tid = threadIdx.x;
  int w = tid >> 6, l = tid & 63;
  int mh = w >> 2, nq = w & 3;
  int o0w = mh * 64;
  int l15 = l & 15, l4 = l >> 4;

  __shared__ __align__(16) f16 sxR[4 * 192 * 8];   // 12 KB
  __shared__ __align__(16) f16 swR[4 * 128 * 8];   // 8 KB

  f32x4 acc[4][3];
#pragma unroll
  for (int mf = 0; mf < 4; ++mf)
#pragma unroll
    for (int nf = 0; nf < 3; ++nf) acc[mf][nf] = (f32x4){0.f, 0.f, 0.f, 0.f};

  for (int ch = 0; ch < 8; ++ch) {
    for (int flat = tid; flat < 768; flat += 512) {
      int cig = flat / 192, px = flat % 192;
      int R = r0 + px / 96, CP = px % 96;
      *(uint4*)(sxR + (cig * 192 + px) * 8) =
          *(const uint4*)(xt + ((size_t)(b * 96 + R) * 96 + CP) * 256 + ch * 32 + cig * 8);
    }
    {
      int cig = tid >> 7, o = tid & 127;
      *(uint4*)(swR + (cig * 128 + o) * 8) =
          *(const uint4*)(wrf + ((size_t)(b * 8 + ch) * 512 + cig * 128 + o) * 8);
    }
    __syncthreads();
    f16x8 af[4];
#pragma unroll
    for (int mf = 0; mf < 4; ++mf)
      af[mf] = *(const f16x8*)(swR + (l4 * 128 + o0w + mf * 16 + l15) * 8);
    f16x8 bf[3];
#pragma unroll
    for (int nf = 0; nf < 3; ++nf)
      bf[nf] = *(const f16x8*)(sxR + (l4 * 192 + nq * 48 + nf * 16 + l15) * 8);
#pragma unroll
    for (int mf = 0; mf < 4; ++mf)
#pragma unroll
      for (int nf = 0; nf < 3; ++nf)
        acc[mf][nf] = __builtin_amdgcn_mfma_f32_16x16x32_f16(af[mf], bf[nf], acc[mf][nf], 0, 0, 0);
    __syncthreads();
  }

#pragma unroll
  for (int mf = 0; mf < 4; ++mf) {
#pragma unroll
    for (int reg = 0; reg < 4; ++reg) {
      int o = o0w + mf * 16 + l4 * 4 + reg;
      float s = 0.f, q = 0.f;
#pragma unroll
      for (int nf = 0; nf < 3; ++nf) {
        float v = acc[mf][nf][reg];
        int px = nq * 48 + nf * 16 + l15;
        int R = r0 + px / 96, CP = px % 96;
        dsth[((size_t)(b * C1 + o) * 96 + R) * 96 + CP] = (f16)v;
        s += v; q += v * v;
      }
#pragma unroll
      for (int m = 1; m < 16; m <<= 1) { s += __shfl_xor(s, m); q += __shfl_xor(q, m); }
      if (l15 == 0) {
        atomicAdd(&ssum[b * C1 + o], s);
        atomicAdd(&ssq[b * C1 + o], q);
      }
    }
  }
}

// ---------------------------------------------------------------------------
// BUF1 f32 NCHW + stats -> lrelu(instnorm) -> XT2 fp16 NHWC [b][r][c][128] + O1SUM
__global__ __launch_bounds__(256) void k_norm1x(const float* __restrict__ buf,
                                                const float* __restrict__ ssum,
                                                const float* __restrict__ ssq,
                                                f16* __restrict__ xt2,
                                                float* __restrict__ osum) {
  int b = blockIdx.y, r = blockIdx.x;
  __shared__ f16 slab[96 * 128];
  __shared__ float mtab[128], rtab[128];
  int t = threadIdx.x;
  if (t < 128) {
    float m = ssum[b * C1 + t] * (1.0f / NPIX);
    float v = ssq[b * C1 + t] * (1.0f / NPIX) - m * m;
    mtab[t] = m; rtab[t] = rsqrtf(v + 1e-5f);
  }
  __syncthreads();
  int c = t & 127, half = t >> 7;
  const float* src = buf + ((size_t)(b * C1 + c) * HO + r) * WO + half * 48;
  float m = mtab[c], ri = rtab[c], sum = 0.f;
#pragma unroll
  for (int j = 0; j < 48; j += 4) {
    float4 v = *(const float4*)(src + j);
    float x0 = (v.x - m) * ri; x0 = x0 >= 0.f ? x0 : 0.01f * x0;
    float x1 = (v.y - m) * ri; x1 = x1 >= 0.f ? x1 : 0.01f * x1;
    float x2 = (v.z - m) * ri; x2 = x2 >= 0.f ? x2 : 0.01f * x2;
    float x3 = (v.w - m) * ri; x3 = x3 >= 0.f ? x3 : 0.01f * x3;
    slab[(half * 48 + j + 0) * 128 + c] = (f16)x0;
    slab[(half * 48 + j + 1) * 128 + c] = (f16)x1;
    slab[(half * 48 + j + 2) * 128 + c] = (f16)x2;
    slab[(half * 48 + j + 3) * 128 + c] = (f16)x3;
    sum += x0 + x1 + x2 + x3;
  }
  atomicAdd(&osum[b * C1 + c], sum);
  __syncthreads();
  uint4* dstv = (uint4*)(xt2 + (size_t)(b * 96 + r) * 96 * 128);
  const uint4* sv = (const uint4*)slab;
#pragma unroll
  for (int i = 0; i < 6; ++i) dstv[i * 256 + t] = sv[i * 256 + t];
}

// ---------------------------------------------------------------------------
__global__ __launch_bounds__(256) void k_final(const float* __restrict__ b2,
                                               const f16* __restrict__ b3,
                                               const float* __restrict__ s2s,
                                               const float* __restrict__ s2q,
                                               const float* __restrict__ s3s,
                                               const float* __restrict__ s3q,
                                               float* __restrict__ out) {
  int bc = blockIdx.x;
  float m2 = s2s[bc] * (1.0f / NPIX);
  float v2 = s2q[bc] * (1.0f / NPIX) - m2 * m2;
  float r2 = rsqrtf(v2 + 1e-5f);
  float m3 = s3s[bc] * (1.0f / NPIX);
  float v3 = s3q[bc] * (1.0f / NPIX) - m3 * m3;
  float r3 = rsqrtf(v3 + 1e-5f);
  const float4* p2 = (const float4*)(b2 + (size_t)bc * NPIX);
  const f16x4* p3 = (const f16x4*)(b3 + (size_t)bc * NPIX);
  float4* po = (float4*)(out + (size_t)bc * NPIX);
#pragma unroll
  for (int it = 0; it < 9; ++it) {
    float4 a = p2[it * 256 + threadIdx.x];
    f16x4 c = p3[it * 256 + threadIdx.x];
    float* aa = (float*)&a;
#pragma unroll
    for (int u = 0; u < 4; ++u) {
      float x = (aa[u] - m2) * r2 + ((float)c[u] - m3) * r3;
      aa[u] = (x >= 0.f) ? x : 0.01f * x;
    }
    po[it * 256 + threadIdx.x] = a;
  }
}

// ---------------------------------------------------------------------------
extern "C" void kernel_launch(void* const* d_in, const int* in_sizes, int n_in,
                              void* d_out, int out_size, void* d_ws, size_t ws_size,
                              hipStream_t stream) {
  const float* inp  = (const float*)d_in[0];
  const float* skip = (const float*)d_in[1];
  const float* wt   = (const float*)d_in[2];
  const float* c1w  = (const float*)d_in[3];
  const float* Wg1  = (const float*)d_in[4];
  const float* bg1  = (const float*)d_in[5];
  const float* A1   = (const float*)d_in[6];
  const float* c2w  = (const float*)d_in[7];
  const float* Wg2  = (const float*)d_in[8];
  const float* bg2  = (const float*)d_in[9];
  const float* A2   = (const float*)d_in[10];
  const float* c3w  = (const float*)d_in[11];
  const float* Wg3  = (const float*)d_in[12];
  const float* bg3  = (const float*)d_in[13];
  const float* A3   = (const float*)d_in[14];

  float* ws = (float*)d_ws;
  float* A    = ws + OFF_A;            // BUF1 -> BUF2
  f16*  B3h   = (f16*)(ws + OFF_B3);
  f16*  XT    = (f16*)(ws + OFF_XT);   // XT2 aliases
  f16*  W1F   = (f16*)(ws + OFF_W1F);  // W2F aliases
  f16*  WRF   = (f16*)(ws + OFF_WRF);
  f16*  WUP   = (f16*)(ws + OFF_WUP);
  float* XSUM = ws + OFF_XSUM;
  float* O1S  = ws + OFF_O1SUM;
  float* G1   = ws + OFF_G1;
  float* G2   = ws + OFF_G2;
  float* G3   = ws + OFF_G3;
  float* S1S = ws + OFF_STATS;
  float* S1Q = S1S + 2048;
  float* S2S = S1Q + 2048;
  float* S2Q = S2S + 2048;
  float* S3S = S2Q + 2048;
  float* S3Q = S3S + 2048;

  hipMemsetAsync(XSUM, 0, 18624 * sizeof(float), stream);

  k_foldup<<<64, 256, 0, stream>>>(wt, WUP);
  k_upT<<<dim3(24, NB), 512, 0, stream>>>(inp, WUP, XT, XSUM);
  k_cvts<<<dim3(96, NB), 256, 0, stream>>>(skip, XT, XSUM);
  k_gate<<<NB, 256, 0, stream>>>(XSUM, C2, 1.0f / NPIX, Wg1, bg1, G1);
  k_gate<<<NB, 256, 0, stream>>>(XSUM, C2, 1.0f / NPIX, Wg3, bg3, G3);
  k_fold<256, 9, false><<<2304, 256, 0, stream>>>(c1w, A1, G1, W1F);
  k_fold<256, 1, true><<<256, 256, 0, stream>>>(c3w, A3, G3, WRF);
  k_cgemm<256, true, false><<<dim3(24, 1, NB), 512, 0, stream>>>(XT, W1F, A, nullptr, S1S, S1Q);
  k_rgemm<<<dim3(48, NB), 512, 0, stream>>>(XT, WRF, B3h, S3S, S3Q);
  k_norm1x<<<dim3(96, NB), 256, 0, stream>>>(A, S1S, S1Q, XT, O1S);
  k_gate<<<NB, 256, 0, stream>>>(O1S, C1, 1.0f / NPIX, Wg2, bg2, G2);
  k_fold<128, 9, false><<<1152, 256, 0, stream>>>(c2w, A2, G2, W1F);
  k_cgemm<128, true, false><<<dim3(24, 1, NB), 512, 0, stream>>>(XT, W1F, A, nullptr, S2S, S2Q);
  k_final<<<NB * C1, 256, 0, stream>>>(A, B3h, S2S, S2Q, S3S, S3Q, (float*)d_out);
}